// Round 2
// baseline (366.951 us; speedup 1.0000x reference)
//
#include <hip/hip_runtime.h>

constexpr int Hh = 320, Ww = 320, Cc = 32, Bb = 4, Nn = 20000;
constexpr int HWp = Hh * Ww;

// grid[src][b][y*W+x] = point index (src 0 = li coords, 1 = ra coords), -1 = empty
__global__ __launch_bounds__(256) void build_grid_k(
    const int* __restrict__ li_coors, const int* __restrict__ ra_coors,
    int* __restrict__ grids) {
  int idx = blockIdx.x * 256 + threadIdx.x;
  if (idx >= 2 * Bb * Nn) return;
  int src = idx / (Bb * Nn);
  int r = idx - src * (Bb * Nn);
  int b = r / Nn, n = r - b * Nn;
  const int* c = (src == 0 ? li_coors : ra_coors) + ((size_t)b * Nn + n) * 2;
  grids[((size_t)src * Bb + b) * HWp + c[0] * Ww + c[1]] = n;
}

// posv[dir][l][c] = pos[l] @ wv_dir.T  (wv = rows 64..95 of in_w)
__global__ __launch_bounds__(256) void posv_k(
    const float* __restrict__ pos, const float* __restrict__ in_w1,
    const float* __restrict__ in_w2, float* __restrict__ posv) {
  int t = blockIdx.x * 256 + threadIdx.x;
  if (t >= 2 * 9 * Cc) return;
  int dir = t / (9 * Cc);
  int rem = t - dir * 9 * Cc;
  int l = rem / Cc, ch = rem - l * Cc;
  const float* w = (dir == 0 ? in_w1 : in_w2) + (2 * Cc + ch) * Cc;
  const float* pl = pos + l * Cc;
  float acc = 0.f;
  for (int j = 0; j < Cc; j++) acc += pl[j] * w[j];
  posv[t] = acc;
}

// K/V projection with fully-coalesced stores.
// Block = 256 threads = 32 points x 8 channel-quads. Thread (p, c4) computes
// float4 of channels [4*c4 .. 4*c4+3] for K and V of point p.
// Store addr = n*32 + c4*4 -> consecutive lanes -> consecutive float4s.
__global__ __launch_bounds__(256) void project_kv_k(
    const float* __restrict__ li_feats, const float* __restrict__ ra_feats,
    const float* __restrict__ in_w1, const float* __restrict__ in_w2,
    float* __restrict__ Kp, float* __restrict__ Vp) {
  int sb = blockIdx.y;
  int src = sb >> 2, b = sb & 3;
  // weights transposed, rows padded to 36 floats (9 float4) for bank spread
  __shared__ __align__(16) float wkT[32 * 36];
  __shared__ __align__(16) float wvT[32 * 36];
  const float* wB = src == 0 ? in_w2 : in_w1;  // k/v weights: other direction
  int t = threadIdx.x;
  for (int i = t; i < Cc * Cc; i += 256) {
    int c = i >> 5, j = i & 31;
    wkT[j * 36 + c] = wB[Cc * Cc + i];
    wvT[j * 36 + c] = wB[2 * Cc * Cc + i];
  }
  __syncthreads();
  int pl = t >> 3, c4 = t & 7;
  int n = blockIdx.x * 32 + pl;  // 625*32 == 20000 exactly, no tail
  const float* f = (src == 0 ? li_feats : ra_feats) + ((size_t)b * Nn + n) * Cc;
  float fv[32];
  const float4* fp = (const float4*)f;
#pragma unroll
  for (int j4 = 0; j4 < 8; j4++) {
    float4 v = fp[j4];
    fv[4 * j4 + 0] = v.x; fv[4 * j4 + 1] = v.y;
    fv[4 * j4 + 2] = v.z; fv[4 * j4 + 3] = v.w;
  }
  const float4* wk4 = (const float4*)wkT;
  const float4* wv4 = (const float4*)wvT;
  float4 ak = make_float4(0.f, 0.f, 0.f, 0.f);
  float4 av = make_float4(0.f, 0.f, 0.f, 0.f);
#pragma unroll
  for (int j = 0; j < 32; j++) {
    float fj = fv[j];
    float4 k4 = wk4[j * 9 + c4];
    float4 v4 = wv4[j * 9 + c4];
    ak.x += fj * k4.x; ak.y += fj * k4.y; ak.z += fj * k4.z; ak.w += fj * k4.w;
    av.x += fj * v4.x; av.y += fj * v4.y; av.z += fj * v4.z; av.w += fj * v4.w;
  }
  int dirkv = 1 - src;
  size_t base = (((size_t)dirkv * Bb + b) * Nn + n) * Cc + c4 * 4;
  *(float4*)(Kp + base) = ak;
  *(float4*)(Vp + base) = av;
}

// Per query point: fused Q projection + 9-slot attention (2 heads of 16)
// + output projection; stores staged through padded LDS for coalescing.
__global__ __launch_bounds__(256) void attn_k(
    const float* __restrict__ li_feats, const float* __restrict__ ra_feats,
    const int* __restrict__ li_coors, const int* __restrict__ ra_coors,
    const int* __restrict__ grids,
    const float* __restrict__ Kp, const float* __restrict__ Vp,
    const float* __restrict__ posv,
    const float* __restrict__ in_w1, const float* __restrict__ in_b1,
    const float* __restrict__ in_b2, const float* __restrict__ in_w2,
    const float* __restrict__ out_w1, const float* __restrict__ out_b1,
    const float* __restrict__ out_w2, const float* __restrict__ out_b2,
    float* __restrict__ out_pts) {
  int db = blockIdx.y;
  int dir = db >> 2, b = db & 3;
  __shared__ __align__(16) float wq[Cc * Cc];
  __shared__ __align__(16) float ow[Cc * Cc];
  __shared__ __align__(16) float pv[9 * Cc];
  __shared__ float obias[Cc], bq[Cc], bk[Cc], bv[Cc];
  __shared__ __align__(16) float ostage[256 * 36];
  const float* wqp = dir == 0 ? in_w1 : in_w2;
  const float* ibp = dir == 0 ? in_b1 : in_b2;
  const float* owp = dir == 0 ? out_w1 : out_w2;
  const float* obp = dir == 0 ? out_b1 : out_b2;
  int t = threadIdx.x;
  for (int i = t; i < Cc * Cc; i += 256) {
    wq[i] = wqp[i];
    ow[i] = owp[i];
  }
  for (int i = t; i < 9 * Cc; i += 256) pv[i] = posv[dir * 9 * Cc + i];
  if (t < Cc) {
    obias[t] = obp[t];
    bq[t] = ibp[t];
    bk[t] = ibp[Cc + t];
    bv[t] = ibp[2 * Cc + t];
  }
  __syncthreads();
  int n = blockIdx.x * 256 + t;
  if (n < Nn) {
    // ---- Q projection (uniform LDS weight reads -> broadcast, conflict-free)
    const float* f =
        (dir == 0 ? li_feats : ra_feats) + ((size_t)b * Nn + n) * Cc;
    float4 fr[8];
    const float4* fp4 = (const float4*)f;
#pragma unroll
    for (int j = 0; j < 8; j++) fr[j] = fp4[j];
    float qh[Cc];
    const float4* wq4 = (const float4*)wq;
#pragma unroll
    for (int c = 0; c < Cc; c++) {
      float acc = bq[c];
#pragma unroll
      for (int j4 = 0; j4 < 8; j4++) {
        float4 w4 = wq4[c * 8 + j4];
        float4 f4 = fr[j4];
        acc += f4.x * w4.x + f4.y * w4.y + f4.z * w4.z + f4.w * w4.w;
      }
      qh[c] = acc;
    }
    // ---- attention
    const int* qc = (dir == 0 ? li_coors : ra_coors) + ((size_t)b * Nn + n) * 2;
    int y = qc[0], x = qc[1];
    const int* g = grids + ((size_t)(1 - dir) * Bb + b) * HWp;
    // invalid-slot score: qh . bk / 4 per head
    float sinv0 = 0.f, sinv1 = 0.f;
#pragma unroll
    for (int j = 0; j < 16; j++) sinv0 += qh[j] * bk[j];
#pragma unroll
    for (int j = 16; j < Cc; j++) sinv1 += qh[j] * bk[j];
    sinv0 *= 0.25f;
    sinv1 *= 0.25f;
    const int DY[9] = {0, -1, 1, 0, -1, 1, 0, -1, 1};
    const int DX[9] = {0, 0, 0, 1, 1, 1, -1, -1, -1};
    int sel[9];
    float s0[9], s1[9];
    const float* Kpb = Kp + ((size_t)dir * Bb + b) * Nn * Cc;
#pragma unroll
    for (int l = 0; l < 9; l++) {
      int cy = y + DY[l], cx = x + DX[l];
      int se = -1;
      if ((unsigned)cy < (unsigned)Hh && (unsigned)cx < (unsigned)Ww)
        se = g[cy * Ww + cx];
      sel[l] = se;
      float d0 = 0.f, d1 = 0.f;
      if (se >= 0) {
        const float4* kp = (const float4*)(Kpb + (size_t)se * Cc);
#pragma unroll
        for (int j4 = 0; j4 < 8; j4++) {
          float4 k4 = kp[j4];
          float a = qh[j4 * 4] * k4.x + qh[j4 * 4 + 1] * k4.y +
                    qh[j4 * 4 + 2] * k4.z + qh[j4 * 4 + 3] * k4.w;
          if (j4 < 4) d0 += a; else d1 += a;
        }
      }
      s0[l] = sinv0 + 0.25f * d0;
      s1[l] = sinv1 + 0.25f * d1;
    }
    float m0 = s0[0], m1 = s1[0];
#pragma unroll
    for (int l = 1; l < 9; l++) { m0 = fmaxf(m0, s0[l]); m1 = fmaxf(m1, s1[l]); }
    float sum0 = 0.f, sum1 = 0.f;
#pragma unroll
    for (int l = 0; l < 9; l++) {
      s0[l] = __expf(s0[l] - m0);
      s1[l] = __expf(s1[l] - m1);
      sum0 += s0[l];
      sum1 += s1[l];
    }
    float o[Cc];
#pragma unroll
    for (int j = 0; j < Cc; j++) o[j] = 0.f;
    const float* Vpb = Vp + ((size_t)dir * Bb + b) * Nn * Cc;
    const float4* pv4 = (const float4*)pv;
#pragma unroll
    for (int l = 0; l < 9; l++) {
      int se = sel[l];
      if (se >= 0) {
        const float4* vp = (const float4*)(Vpb + (size_t)se * Cc);
        float w0 = s0[l], w1 = s1[l];
#pragma unroll
        for (int j4 = 0; j4 < 8; j4++) {
          float4 v4 = vp[j4];
          float4 p4 = pv4[l * 8 + j4];
          float w = (j4 < 4) ? w0 : w1;
          o[j4 * 4 + 0] += w * (v4.x + p4.x);
          o[j4 * 4 + 1] += w * (v4.y + p4.y);
          o[j4 * 4 + 2] += w * (v4.z + p4.z);
          o[j4 * 4 + 3] += w * (v4.w + p4.w);
        }
      }
    }
    float r0 = 1.f / sum0, r1 = 1.f / sum1;
#pragma unroll
    for (int j = 0; j < 16; j++) o[j] = o[j] * r0 + bv[j];
#pragma unroll
    for (int j = 16; j < Cc; j++) o[j] = o[j] * r1 + bv[j];
    // ---- output projection into padded LDS staging
    const float4* ow4 = (const float4*)ow;
#pragma unroll
    for (int c0 = 0; c0 < Cc; c0 += 4) {
      float a[4];
#pragma unroll
      for (int u = 0; u < 4; u++) {
        float acc = obias[c0 + u];
#pragma unroll
        for (int j4 = 0; j4 < 8; j4++) {
          float4 w4 = ow4[(c0 + u) * 8 + j4];
          acc += o[j4 * 4 + 0] * w4.x + o[j4 * 4 + 1] * w4.y +
                 o[j4 * 4 + 2] * w4.z + o[j4 * 4 + 3] * w4.w;
        }
        a[u] = acc;
      }
      *(float4*)(ostage + t * 36 + c0) = make_float4(a[0], a[1], a[2], a[3]);
    }
  }
  __syncthreads();
  // ---- coalesced copy-out: 2048 float4s (256 points x 8) by 256 threads
  size_t n0 = (size_t)blockIdx.x * 256;
  size_t gbase = (((size_t)dir * Bb + b) * Nn + n0) * Cc;  // float index
  float4* outp = (float4*)(out_pts + gbase);
  size_t remain_f4 = (Nn > n0) ? (Nn - n0) * 8 : 0;
#pragma unroll
  for (int i = 0; i < 8; i++) {
    int m = i * 256 + t;  // float4 index within block tile
    if ((size_t)m < remain_f4) {
      int p = m >> 3, c4 = m & 7;
      outp[m] = *(const float4*)(ostage + p * 36 + c4 * 4);
    }
  }
}

// Inverted scatter: one thread per canvas pixel; channel stores are wave-coalesced.
__global__ __launch_bounds__(256) void scatter_k(
    const int* __restrict__ grids, const float* __restrict__ out_pts,
    float* __restrict__ out) {
  int db = blockIdx.y;
  int dir = db >> 2, b = db & 3;
  int p = blockIdx.x * 256 + threadIdx.x;
  const int* g = grids + ((size_t)dir * Bb + b) * HWp;
  int se = g[p];
  float* ob = out + (((size_t)dir * Bb + b) * Cc) * HWp + p;
  if (se < 0) {
#pragma unroll
    for (int c = 0; c < Cc; c++) ob[(size_t)c * HWp] = 0.f;
  } else {
    const float4* sp =
        (const float4*)(out_pts + (((size_t)dir * Bb + b) * Nn + se) * Cc);
#pragma unroll
    for (int c4 = 0; c4 < 8; c4++) {
      float4 v = sp[c4];
      ob[(size_t)(c4 * 4 + 0) * HWp] = v.x;
      ob[(size_t)(c4 * 4 + 1) * HWp] = v.y;
      ob[(size_t)(c4 * 4 + 2) * HWp] = v.z;
      ob[(size_t)(c4 * 4 + 3) * HWp] = v.w;
    }
  }
}

extern "C" void kernel_launch(void* const* d_in, const int* in_sizes, int n_in,
                              void* d_out, int out_size, void* d_ws, size_t ws_size,
                              hipStream_t stream) {
  const float* li_feats = (const float*)d_in[0];
  const int* li_coors = (const int*)d_in[1];
  const float* ra_feats = (const float*)d_in[2];
  const int* ra_coors = (const int*)d_in[3];
  const float* pos = (const float*)d_in[4];
  const float* in_w1 = (const float*)d_in[5];
  const float* in_b1 = (const float*)d_in[6];
  const float* out_w1 = (const float*)d_in[7];
  const float* out_b1 = (const float*)d_in[8];
  const float* in_w2 = (const float*)d_in[9];
  const float* in_b2 = (const float*)d_in[10];
  const float* out_w2 = (const float*)d_in[11];
  const float* out_b2 = (const float*)d_in[12];

  char* ws = (char*)d_ws;
  size_t off = 0;
  int* grids = (int*)(ws + off);
  off += (size_t)2 * Bb * HWp * 4;  // 3,276,800 B
  float* Kp = (float*)(ws + off);
  off += (size_t)2 * Bb * Nn * Cc * 4;  // 20,480,000 B
  float* Vp = (float*)(ws + off);
  off += (size_t)2 * Bb * Nn * Cc * 4;
  float* out_pts = (float*)(ws + off);
  off += (size_t)2 * Bb * Nn * Cc * 4;
  float* posv = (float*)(ws + off);
  off += (size_t)2 * 9 * Cc * 4;  // total ~64.7 MB

  hipMemsetAsync(grids, 0xFF, (size_t)2 * Bb * HWp * 4, stream);
  build_grid_k<<<(2 * Bb * Nn + 255) / 256, 256, 0, stream>>>(li_coors, ra_coors,
                                                              grids);
  posv_k<<<3, 256, 0, stream>>>(pos, in_w1, in_w2, posv);
  dim3 gkv(Nn / 32, 2 * Bb);
  project_kv_k<<<gkv, 256, 0, stream>>>(li_feats, ra_feats, in_w1, in_w2, Kp, Vp);
  dim3 ga((Nn + 255) / 256, 2 * Bb);
  attn_k<<<ga, 256, 0, stream>>>(li_feats, ra_feats, li_coors, ra_coors, grids, Kp,
                                 Vp, posv, in_w1, in_b1, in_b2, in_w2, out_w1,
                                 out_b1, out_w2, out_b2, out_pts);
  dim3 gs(HWp / 256, 2 * Bb);
  scatter_k<<<gs, 256, 0, stream>>>(grids, out_pts, (float*)d_out);
}

// Round 3
// 105.079 us; speedup vs baseline: 3.4921x; 3.4921x over previous
//
#include <hip/hip_runtime.h>

constexpr int Hh = 320, Ww = 320, Cc = 32, Bb = 4, Nn = 20000;
constexpr int HWp = Hh * Ww;

// grid[src][b][y*W+x] = point index (src 0 = li coords, 1 = ra coords), -1 = empty
__global__ __launch_bounds__(256) void build_grid_k(
    const int* __restrict__ li_coors, const int* __restrict__ ra_coors,
    int* __restrict__ grids) {
  int idx = blockIdx.x * 256 + threadIdx.x;
  if (idx >= 2 * Bb * Nn) return;
  int src = idx / (Bb * Nn);
  int r = idx - src * (Bb * Nn);
  int b = r / Nn, n = r - b * Nn;
  const int* c = (src == 0 ? li_coors : ra_coors) + ((size_t)b * Nn + n) * 2;
  grids[((size_t)src * Bb + b) * HWp + c[0] * Ww + c[1]] = n;
}

// posv[dir][l][c] = pos[l] @ wv_dir.T  (wv = rows 64..95 of in_w)
__global__ __launch_bounds__(256) void posv_k(
    const float* __restrict__ pos, const float* __restrict__ in_w1,
    const float* __restrict__ in_w2, float* __restrict__ posv) {
  int t = blockIdx.x * 256 + threadIdx.x;
  if (t >= 2 * 9 * Cc) return;
  int dir = t / (9 * Cc);
  int rem = t - dir * 9 * Cc;
  int l = rem / Cc, ch = rem - l * Cc;
  const float* w = (dir == 0 ? in_w1 : in_w2) + (2 * Cc + ch) * Cc;
  const float* pl = pos + l * Cc;
  float acc = 0.f;
  for (int j = 0; j < Cc; j++) acc += pl[j] * w[j];
  posv[t] = acc;
}

// Q/K/V projection with fully-coalesced stores.
// Block = 256 threads = 32 points x 8 channel-quads. Thread (p, c4) computes
// the float4 of channels [4*c4 .. 4*c4+3] for Q (own dir, +bias), K and V
// (other dir, no bias -- bias handled analytically in attn_k).
// Store addr = n*32 + c4*4 -> consecutive lanes -> consecutive float4s.
__global__ __launch_bounds__(256) void project_qkv_k(
    const float* __restrict__ li_feats, const float* __restrict__ ra_feats,
    const float* __restrict__ in_w1, const float* __restrict__ in_b1,
    const float* __restrict__ in_w2, const float* __restrict__ in_b2,
    float* __restrict__ Qh, float* __restrict__ Kp, float* __restrict__ Vp) {
  int sb = blockIdx.y;
  int src = sb >> 2, b = sb & 3;
  // weights transposed, rows padded to 36 floats (9 float4) for bank spread
  __shared__ __align__(16) float wqT[32 * 36];
  __shared__ __align__(16) float wkT[32 * 36];
  __shared__ __align__(16) float wvT[32 * 36];
  __shared__ float bq[Cc];
  const float* wA = src == 0 ? in_w1 : in_w2;  // q weights: own direction
  const float* bA = src == 0 ? in_b1 : in_b2;
  const float* wB = src == 0 ? in_w2 : in_w1;  // k/v weights: other direction
  int t = threadIdx.x;
  for (int i = t; i < Cc * Cc; i += 256) {
    int c = i >> 5, j = i & 31;
    wqT[j * 36 + c] = wA[i];
    wkT[j * 36 + c] = wB[Cc * Cc + i];
    wvT[j * 36 + c] = wB[2 * Cc * Cc + i];
  }
  if (t < Cc) bq[t] = bA[t];
  __syncthreads();
  int pl = t >> 3, c4 = t & 7;
  int n = blockIdx.x * 32 + pl;  // 625*32 == 20000 exactly, no tail
  const float* f = (src == 0 ? li_feats : ra_feats) + ((size_t)b * Nn + n) * Cc;
  float fv[32];
  const float4* fp = (const float4*)f;
#pragma unroll
  for (int j4 = 0; j4 < 8; j4++) {
    float4 v = fp[j4];
    fv[4 * j4 + 0] = v.x; fv[4 * j4 + 1] = v.y;
    fv[4 * j4 + 2] = v.z; fv[4 * j4 + 3] = v.w;
  }
  const float4* wq4 = (const float4*)wqT;
  const float4* wk4 = (const float4*)wkT;
  const float4* wv4 = (const float4*)wvT;
  float4 aq = *(const float4*)(bq + c4 * 4);
  float4 ak = make_float4(0.f, 0.f, 0.f, 0.f);
  float4 av = make_float4(0.f, 0.f, 0.f, 0.f);
#pragma unroll
  for (int j = 0; j < 32; j++) {
    float fj = fv[j];
    float4 q4 = wq4[j * 9 + c4];
    float4 k4 = wk4[j * 9 + c4];
    float4 v4 = wv4[j * 9 + c4];
    aq.x += fj * q4.x; aq.y += fj * q4.y; aq.z += fj * q4.z; aq.w += fj * q4.w;
    ak.x += fj * k4.x; ak.y += fj * k4.y; ak.z += fj * k4.z; ak.w += fj * k4.w;
    av.x += fj * v4.x; av.y += fj * v4.y; av.z += fj * v4.z; av.w += fj * v4.w;
  }
  int dirq = src, dirkv = 1 - src;
  size_t qbase = (((size_t)dirq * Bb + b) * Nn + n) * Cc + c4 * 4;
  size_t kvbase = (((size_t)dirkv * Bb + b) * Nn + n) * Cc + c4 * 4;
  *(float4*)(Qh + qbase) = aq;
  *(float4*)(Kp + kvbase) = ak;
  *(float4*)(Vp + kvbase) = av;
}

// Per query point: 9-slot attention (2 heads of 16) + output projection.
// (round-1 proven version: low VGPR, no scratch, no big LDS staging)
__global__ __launch_bounds__(256) void attn_k(
    const int* __restrict__ li_coors, const int* __restrict__ ra_coors,
    const int* __restrict__ grids, const float* __restrict__ Qh,
    const float* __restrict__ Kp, const float* __restrict__ Vp,
    const float* __restrict__ posv, const float* __restrict__ in_b1,
    const float* __restrict__ in_b2, const float* __restrict__ out_w1,
    const float* __restrict__ out_b1, const float* __restrict__ out_w2,
    const float* __restrict__ out_b2, float* __restrict__ out_pts) {
  int db = blockIdx.y;
  int dir = db >> 2, b = db & 3;
  __shared__ __align__(16) float ow[Cc * Cc];
  __shared__ __align__(16) float pv[9 * Cc];
  __shared__ float obias[Cc], bk[Cc], bv[Cc];
  const float* owp = dir == 0 ? out_w1 : out_w2;
  const float* obp = dir == 0 ? out_b1 : out_b2;
  const float* ibp = dir == 0 ? in_b1 : in_b2;
  int t = threadIdx.x;
  for (int i = t; i < Cc * Cc; i += 256) ow[i] = owp[i];
  for (int i = t; i < 9 * Cc; i += 256) pv[i] = posv[dir * 9 * Cc + i];
  if (t < Cc) { obias[t] = obp[t]; bk[t] = ibp[Cc + t]; bv[t] = ibp[2 * Cc + t]; }
  __syncthreads();
  int n = blockIdx.x * 256 + t;
  if (n >= Nn) return;
  const int* qc = (dir == 0 ? li_coors : ra_coors) + ((size_t)b * Nn + n) * 2;
  int y = qc[0], x = qc[1];
  // kv grid: dir0 attends over ra (src1), dir1 over li (src0)
  const int* g = grids + ((size_t)(1 - dir) * Bb + b) * HWp;
  float4 qh4[8];
  const float4* qp = (const float4*)(Qh + (((size_t)dir * Bb + b) * Nn + n) * Cc);
#pragma unroll
  for (int j = 0; j < 8; j++) qh4[j] = qp[j];
  // invalid-slot score: qh . bk / 4 per head (reference keeps zero-K slots in softmax)
  float sinv0 = 0.f, sinv1 = 0.f;
  const float4* bk4 = (const float4*)bk;
#pragma unroll
  for (int j4 = 0; j4 < 4; j4++) {
    float4 b4 = bk4[j4], q4 = qh4[j4];
    sinv0 += q4.x * b4.x + q4.y * b4.y + q4.z * b4.z + q4.w * b4.w;
  }
#pragma unroll
  for (int j4 = 4; j4 < 8; j4++) {
    float4 b4 = bk4[j4], q4 = qh4[j4];
    sinv1 += q4.x * b4.x + q4.y * b4.y + q4.z * b4.z + q4.w * b4.w;
  }
  sinv0 *= 0.25f;
  sinv1 *= 0.25f;
  const int DY[9] = {0, -1, 1, 0, -1, 1, 0, -1, 1};
  const int DX[9] = {0, 0, 0, 1, 1, 1, -1, -1, -1};
  int sel[9];
  float s0[9], s1[9];
  const float* Kpb = Kp + ((size_t)dir * Bb + b) * Nn * Cc;
#pragma unroll
  for (int l = 0; l < 9; l++) {
    int cy = y + DY[l], cx = x + DX[l];
    int se = -1;
    if ((unsigned)cy < (unsigned)Hh && (unsigned)cx < (unsigned)Ww) se = g[cy * Ww + cx];
    sel[l] = se;
    float d0 = 0.f, d1 = 0.f;
    if (se >= 0) {
      const float4* kp = (const float4*)(Kpb + (size_t)se * Cc);
#pragma unroll
      for (int j4 = 0; j4 < 4; j4++) {
        float4 k4 = kp[j4], q4 = qh4[j4];
        d0 += q4.x * k4.x + q4.y * k4.y + q4.z * k4.z + q4.w * k4.w;
      }
#pragma unroll
      for (int j4 = 4; j4 < 8; j4++) {
        float4 k4 = kp[j4], q4 = qh4[j4];
        d1 += q4.x * k4.x + q4.y * k4.y + q4.z * k4.z + q4.w * k4.w;
      }
    }
    s0[l] = sinv0 + 0.25f * d0;
    s1[l] = sinv1 + 0.25f * d1;
  }
  float m0 = s0[0], m1 = s1[0];
#pragma unroll
  for (int l = 1; l < 9; l++) { m0 = fmaxf(m0, s0[l]); m1 = fmaxf(m1, s1[l]); }
  float sum0 = 0.f, sum1 = 0.f;
#pragma unroll
  for (int l = 0; l < 9; l++) {
    s0[l] = __expf(s0[l] - m0);
    s1[l] = __expf(s1[l] - m1);
    sum0 += s0[l];
    sum1 += s1[l];
  }
  float o[Cc];
#pragma unroll
  for (int j = 0; j < Cc; j++) o[j] = 0.f;
  const float* Vpb = Vp + ((size_t)dir * Bb + b) * Nn * Cc;
  const float4* pv4 = (const float4*)pv;
#pragma unroll
  for (int l = 0; l < 9; l++) {
    int se = sel[l];
    if (se >= 0) {
      const float4* vp = (const float4*)(Vpb + (size_t)se * Cc);
      float w0 = s0[l], w1 = s1[l];
#pragma unroll
      for (int j4 = 0; j4 < 8; j4++) {
        float4 v4 = vp[j4];
        float4 p4 = pv4[l * 8 + j4];
        float w = (j4 < 4) ? w0 : w1;
        o[j4 * 4 + 0] += w * (v4.x + p4.x);
        o[j4 * 4 + 1] += w * (v4.y + p4.y);
        o[j4 * 4 + 2] += w * (v4.z + p4.z);
        o[j4 * 4 + 3] += w * (v4.w + p4.w);
      }
    }
  }
  float r0 = 1.f / sum0, r1 = 1.f / sum1;
#pragma unroll
  for (int j = 0; j < 16; j++) o[j] = o[j] * r0 + bv[j];
#pragma unroll
  for (int j = 16; j < Cc; j++) o[j] = o[j] * r1 + bv[j];
  float* op = out_pts + (((size_t)dir * Bb + b) * Nn + n) * Cc;
  const float4* ow4 = (const float4*)ow;
#pragma unroll
  for (int c0 = 0; c0 < Cc; c0 += 4) {
    float a[4];
#pragma unroll
    for (int u = 0; u < 4; u++) {
      float acc = obias[c0 + u];
#pragma unroll
      for (int j4 = 0; j4 < 8; j4++) {
        float4 w4 = ow4[(c0 + u) * 8 + j4];
        acc += o[j4 * 4 + 0] * w4.x + o[j4 * 4 + 1] * w4.y + o[j4 * 4 + 2] * w4.z +
               o[j4 * 4 + 3] * w4.w;
      }
      a[u] = acc;
    }
    *(float4*)(op + c0) = make_float4(a[0], a[1], a[2], a[3]);
  }
}

// Inverted scatter: one thread per canvas pixel; channel stores are wave-coalesced.
__global__ __launch_bounds__(256) void scatter_k(
    const int* __restrict__ grids, const float* __restrict__ out_pts,
    float* __restrict__ out) {
  int db = blockIdx.y;
  int dir = db >> 2, b = db & 3;
  int p = blockIdx.x * 256 + threadIdx.x;
  const int* g = grids + ((size_t)dir * Bb + b) * HWp;
  int se = g[p];
  float* ob = out + (((size_t)dir * Bb + b) * Cc) * HWp + p;
  if (se < 0) {
#pragma unroll
    for (int c = 0; c < Cc; c++) ob[(size_t)c * HWp] = 0.f;
  } else {
    const float4* sp =
        (const float4*)(out_pts + (((size_t)dir * Bb + b) * Nn + se) * Cc);
#pragma unroll
    for (int c4 = 0; c4 < 8; c4++) {
      float4 v = sp[c4];
      ob[(size_t)(c4 * 4 + 0) * HWp] = v.x;
      ob[(size_t)(c4 * 4 + 1) * HWp] = v.y;
      ob[(size_t)(c4 * 4 + 2) * HWp] = v.z;
      ob[(size_t)(c4 * 4 + 3) * HWp] = v.w;
    }
  }
}

extern "C" void kernel_launch(void* const* d_in, const int* in_sizes, int n_in,
                              void* d_out, int out_size, void* d_ws, size_t ws_size,
                              hipStream_t stream) {
  const float* li_feats = (const float*)d_in[0];
  const int* li_coors = (const int*)d_in[1];
  const float* ra_feats = (const float*)d_in[2];
  const int* ra_coors = (const int*)d_in[3];
  const float* pos = (const float*)d_in[4];
  const float* in_w1 = (const float*)d_in[5];
  const float* in_b1 = (const float*)d_in[6];
  const float* out_w1 = (const float*)d_in[7];
  const float* out_b1 = (const float*)d_in[8];
  const float* in_w2 = (const float*)d_in[9];
  const float* in_b2 = (const float*)d_in[10];
  const float* out_w2 = (const float*)d_in[11];
  const float* out_b2 = (const float*)d_in[12];

  char* ws = (char*)d_ws;
  size_t off = 0;
  int* grids = (int*)(ws + off);
  off += (size_t)2 * Bb * HWp * 4;  // 3,276,800 B
  float* Qh = (float*)(ws + off);
  off += (size_t)2 * Bb * Nn * Cc * 4;  // 20,480,000 B
  float* Kp = (float*)(ws + off);
  off += (size_t)2 * Bb * Nn * Cc * 4;
  float* Vp = (float*)(ws + off);
  off += (size_t)2 * Bb * Nn * Cc * 4;
  float* out_pts = (float*)(ws + off);
  off += (size_t)2 * Bb * Nn * Cc * 4;
  float* posv = (float*)(ws + off);
  off += (size_t)2 * 9 * Cc * 4;  // total ~85.2 MB

  hipMemsetAsync(grids, 0xFF, (size_t)2 * Bb * HWp * 4, stream);
  build_grid_k<<<(2 * Bb * Nn + 255) / 256, 256, 0, stream>>>(li_coors, ra_coors,
                                                              grids);
  posv_k<<<3, 256, 0, stream>>>(pos, in_w1, in_w2, posv);
  dim3 gkv(Nn / 32, 2 * Bb);
  project_qkv_k<<<gkv, 256, 0, stream>>>(li_feats, ra_feats, in_w1, in_b1, in_w2,
                                         in_b2, Qh, Kp, Vp);
  dim3 ga((Nn + 255) / 256, 2 * Bb);
  attn_k<<<ga, 256, 0, stream>>>(li_coors, ra_coors, grids, Qh, Kp, Vp, posv, in_b1,
                                 in_b2, out_w1, out_b1, out_w2, out_b2, out_pts);
  dim3 gs(HWp / 256, 2 * Bb);
  scatter_k<<<gs, 256, 0, stream>>>(grids, out_pts, (float*)d_out);
}

// Round 4
// 104.083 us; speedup vs baseline: 3.5256x; 1.0096x over previous
//
#include <hip/hip_runtime.h>

constexpr int Hh = 320, Ww = 320, Cc = 32, Bb = 4, Nn = 20000;
constexpr int HWp = Hh * Ww;

// Fused prep: blocks [0,800) fill grids with -1 (int4 stores, full BW);
// blocks [800,803) compute posv[dir][l][c] = pos[l] @ wv_dir.T
__global__ __launch_bounds__(256) void prep_k(
    int* __restrict__ grids, const float* __restrict__ pos,
    const float* __restrict__ in_w1, const float* __restrict__ in_w2,
    float* __restrict__ posv) {
  int bx = blockIdx.x;
  if (bx < 800) {
    int i = bx * 256 + threadIdx.x;  // int4 index; 800*256 = 204800 = 2*4*HWp/4
    ((int4*)grids)[i] = make_int4(-1, -1, -1, -1);
    return;
  }
  int t = (bx - 800) * 256 + threadIdx.x;
  if (t >= 2 * 9 * Cc) return;
  int dir = t / (9 * Cc);
  int rem = t - dir * 9 * Cc;
  int l = rem / Cc, ch = rem - l * Cc;
  const float* w = (dir == 0 ? in_w1 : in_w2) + (2 * Cc + ch) * Cc;
  const float* pl = pos + l * Cc;
  float acc = 0.f;
  for (int j = 0; j < Cc; j++) acc += pl[j] * w[j];
  posv[t] = acc;
}

// grid[src][b][y*W+x] = point index (src 0 = li coords, 1 = ra coords), -1 = empty
__global__ __launch_bounds__(256) void build_grid_k(
    const int* __restrict__ li_coors, const int* __restrict__ ra_coors,
    int* __restrict__ grids) {
  int idx = blockIdx.x * 256 + threadIdx.x;
  if (idx >= 2 * Bb * Nn) return;
  int src = idx / (Bb * Nn);
  int r = idx - src * (Bb * Nn);
  int b = r / Nn, n = r - b * Nn;
  const int* c = (src == 0 ? li_coors : ra_coors) + ((size_t)b * Nn + n) * 2;
  grids[((size_t)src * Bb + b) * HWp + c[0] * Ww + c[1]] = n;
}

// Q/K/V projection with fully-coalesced stores.
// Block = 256 threads = 32 points x 8 channel-quads. Thread (p, c4) computes
// the float4 of channels [4*c4 .. 4*c4+3] for Q (own dir, +bias), K and V
// (other dir, no bias -- bias handled analytically in attn_k).
__global__ __launch_bounds__(256) void project_qkv_k(
    const float* __restrict__ li_feats, const float* __restrict__ ra_feats,
    const float* __restrict__ in_w1, const float* __restrict__ in_b1,
    const float* __restrict__ in_w2, const float* __restrict__ in_b2,
    float* __restrict__ Qh, float* __restrict__ Kp, float* __restrict__ Vp) {
  int sb = blockIdx.y;
  int src = sb >> 2, b = sb & 3;
  // weights transposed, rows padded to 36 floats (9 float4) for bank spread
  __shared__ __align__(16) float wqT[32 * 36];
  __shared__ __align__(16) float wkT[32 * 36];
  __shared__ __align__(16) float wvT[32 * 36];
  __shared__ float bq[Cc];
  const float* wA = src == 0 ? in_w1 : in_w2;  // q weights: own direction
  const float* bA = src == 0 ? in_b1 : in_b2;
  const float* wB = src == 0 ? in_w2 : in_w1;  // k/v weights: other direction
  int t = threadIdx.x;
  for (int i = t; i < Cc * Cc; i += 256) {
    int c = i >> 5, j = i & 31;
    wqT[j * 36 + c] = wA[i];
    wkT[j * 36 + c] = wB[Cc * Cc + i];
    wvT[j * 36 + c] = wB[2 * Cc * Cc + i];
  }
  if (t < Cc) bq[t] = bA[t];
  __syncthreads();
  int pl = t >> 3, c4 = t & 7;
  int n = blockIdx.x * 32 + pl;  // 625*32 == 20000 exactly, no tail
  const float* f = (src == 0 ? li_feats : ra_feats) + ((size_t)b * Nn + n) * Cc;
  float fv[32];
  const float4* fp = (const float4*)f;
#pragma unroll
  for (int j4 = 0; j4 < 8; j4++) {
    float4 v = fp[j4];
    fv[4 * j4 + 0] = v.x; fv[4 * j4 + 1] = v.y;
    fv[4 * j4 + 2] = v.z; fv[4 * j4 + 3] = v.w;
  }
  const float4* wq4 = (const float4*)wqT;
  const float4* wk4 = (const float4*)wkT;
  const float4* wv4 = (const float4*)wvT;
  float4 aq = *(const float4*)(bq + c4 * 4);
  float4 ak = make_float4(0.f, 0.f, 0.f, 0.f);
  float4 av = make_float4(0.f, 0.f, 0.f, 0.f);
#pragma unroll
  for (int j = 0; j < 32; j++) {
    float fj = fv[j];
    float4 q4 = wq4[j * 9 + c4];
    float4 k4 = wk4[j * 9 + c4];
    float4 v4 = wv4[j * 9 + c4];
    aq.x += fj * q4.x; aq.y += fj * q4.y; aq.z += fj * q4.z; aq.w += fj * q4.w;
    ak.x += fj * k4.x; ak.y += fj * k4.y; ak.z += fj * k4.z; ak.w += fj * k4.w;
    av.x += fj * v4.x; av.y += fj * v4.y; av.z += fj * v4.z; av.w += fj * v4.w;
  }
  int dirq = src, dirkv = 1 - src;
  size_t qbase = (((size_t)dirq * Bb + b) * Nn + n) * Cc + c4 * 4;
  size_t kvbase = (((size_t)dirkv * Bb + b) * Nn + n) * Cc + c4 * 4;
  *(float4*)(Qh + qbase) = aq;
  *(float4*)(Kp + kvbase) = ak;
  *(float4*)(Vp + kvbase) = av;
}

// Per query point: 9-slot attention (2 heads of 16) + output projection.
__global__ __launch_bounds__(256) void attn_k(
    const int* __restrict__ li_coors, const int* __restrict__ ra_coors,
    const int* __restrict__ grids, const float* __restrict__ Qh,
    const float* __restrict__ Kp, const float* __restrict__ Vp,
    const float* __restrict__ posv, const float* __restrict__ in_b1,
    const float* __restrict__ in_b2, const float* __restrict__ out_w1,
    const float* __restrict__ out_b1, const float* __restrict__ out_w2,
    const float* __restrict__ out_b2, float* __restrict__ out_pts) {
  int db = blockIdx.y;
  int dir = db >> 2, b = db & 3;
  __shared__ __align__(16) float ow[Cc * Cc];
  __shared__ __align__(16) float pv[9 * Cc];
  __shared__ float obias[Cc], bk[Cc], bv[Cc];
  const float* owp = dir == 0 ? out_w1 : out_w2;
  const float* obp = dir == 0 ? out_b1 : out_b2;
  const float* ibp = dir == 0 ? in_b1 : in_b2;
  int t = threadIdx.x;
  for (int i = t; i < Cc * Cc; i += 256) ow[i] = owp[i];
  for (int i = t; i < 9 * Cc; i += 256) pv[i] = posv[dir * 9 * Cc + i];
  if (t < Cc) { obias[t] = obp[t]; bk[t] = ibp[Cc + t]; bv[t] = ibp[2 * Cc + t]; }
  __syncthreads();
  int n = blockIdx.x * 256 + t;
  if (n >= Nn) return;
  const int* qc = (dir == 0 ? li_coors : ra_coors) + ((size_t)b * Nn + n) * 2;
  int y = qc[0], x = qc[1];
  // kv grid: dir0 attends over ra (src1), dir1 over li (src0)
  const int* g = grids + ((size_t)(1 - dir) * Bb + b) * HWp;
  float4 qh4[8];
  const float4* qp = (const float4*)(Qh + (((size_t)dir * Bb + b) * Nn + n) * Cc);
#pragma unroll
  for (int j = 0; j < 8; j++) qh4[j] = qp[j];
  // invalid-slot score: qh . bk / 4 per head (reference keeps zero-K slots in softmax)
  float sinv0 = 0.f, sinv1 = 0.f;
  const float4* bk4 = (const float4*)bk;
#pragma unroll
  for (int j4 = 0; j4 < 4; j4++) {
    float4 b4 = bk4[j4], q4 = qh4[j4];
    sinv0 += q4.x * b4.x + q4.y * b4.y + q4.z * b4.z + q4.w * b4.w;
  }
#pragma unroll
  for (int j4 = 4; j4 < 8; j4++) {
    float4 b4 = bk4[j4], q4 = qh4[j4];
    sinv1 += q4.x * b4.x + q4.y * b4.y + q4.z * b4.z + q4.w * b4.w;
  }
  sinv0 *= 0.25f;
  sinv1 *= 0.25f;
  const int DY[9] = {0, -1, 1, 0, -1, 1, 0, -1, 1};
  const int DX[9] = {0, 0, 0, 1, 1, 1, -1, -1, -1};
  int sel[9];
  float s0[9], s1[9];
  const float* Kpb = Kp + ((size_t)dir * Bb + b) * Nn * Cc;
#pragma unroll
  for (int l = 0; l < 9; l++) {
    int cy = y + DY[l], cx = x + DX[l];
    int se = -1;
    if ((unsigned)cy < (unsigned)Hh && (unsigned)cx < (unsigned)Ww) se = g[cy * Ww + cx];
    sel[l] = se;
    float d0 = 0.f, d1 = 0.f;
    if (se >= 0) {
      const float4* kp = (const float4*)(Kpb + (size_t)se * Cc);
#pragma unroll
      for (int j4 = 0; j4 < 4; j4++) {
        float4 k4 = kp[j4], q4 = qh4[j4];
        d0 += q4.x * k4.x + q4.y * k4.y + q4.z * k4.z + q4.w * k4.w;
      }
#pragma unroll
      for (int j4 = 4; j4 < 8; j4++) {
        float4 k4 = kp[j4], q4 = qh4[j4];
        d1 += q4.x * k4.x + q4.y * k4.y + q4.z * k4.z + q4.w * k4.w;
      }
    }
    s0[l] = sinv0 + 0.25f * d0;
    s1[l] = sinv1 + 0.25f * d1;
  }
  float m0 = s0[0], m1 = s1[0];
#pragma unroll
  for (int l = 1; l < 9; l++) { m0 = fmaxf(m0, s0[l]); m1 = fmaxf(m1, s1[l]); }
  float sum0 = 0.f, sum1 = 0.f;
#pragma unroll
  for (int l = 0; l < 9; l++) {
    s0[l] = __expf(s0[l] - m0);
    s1[l] = __expf(s1[l] - m1);
    sum0 += s0[l];
    sum1 += s1[l];
  }
  float o[Cc];
#pragma unroll
  for (int j = 0; j < Cc; j++) o[j] = 0.f;
  const float* Vpb = Vp + ((size_t)dir * Bb + b) * Nn * Cc;
  const float4* pv4 = (const float4*)pv;
#pragma unroll
  for (int l = 0; l < 9; l++) {
    int se = sel[l];
    if (se >= 0) {
      const float4* vp = (const float4*)(Vpb + (size_t)se * Cc);
      float w0 = s0[l], w1 = s1[l];
#pragma unroll
      for (int j4 = 0; j4 < 8; j4++) {
        float4 v4 = vp[j4];
        float4 p4 = pv4[l * 8 + j4];
        float w = (j4 < 4) ? w0 : w1;
        o[j4 * 4 + 0] += w * (v4.x + p4.x);
        o[j4 * 4 + 1] += w * (v4.y + p4.y);
        o[j4 * 4 + 2] += w * (v4.z + p4.z);
        o[j4 * 4 + 3] += w * (v4.w + p4.w);
      }
    }
  }
  float r0 = 1.f / sum0, r1 = 1.f / sum1;
#pragma unroll
  for (int j = 0; j < 16; j++) o[j] = o[j] * r0 + bv[j];
#pragma unroll
  for (int j = 16; j < Cc; j++) o[j] = o[j] * r1 + bv[j];
  float* op = out_pts + (((size_t)dir * Bb + b) * Nn + n) * Cc;
  const float4* ow4 = (const float4*)ow;
#pragma unroll
  for (int c0 = 0; c0 < Cc; c0 += 4) {
    float a[4];
#pragma unroll
    for (int u = 0; u < 4; u++) {
      float acc = obias[c0 + u];
#pragma unroll
      for (int j4 = 0; j4 < 8; j4++) {
        float4 w4 = ow4[(c0 + u) * 8 + j4];
        acc += o[j4 * 4 + 0] * w4.x + o[j4 * 4 + 1] * w4.y + o[j4 * 4 + 2] * w4.z +
               o[j4 * 4 + 3] * w4.w;
      }
      a[u] = acc;
    }
    *(float4*)(op + c0) = make_float4(a[0], a[1], a[2], a[3]);
  }
}

// Inverted scatter: one thread per canvas pixel; channel stores are wave-coalesced.
__global__ __launch_bounds__(256) void scatter_k(
    const int* __restrict__ grids, const float* __restrict__ out_pts,
    float* __restrict__ out) {
  int db = blockIdx.y;
  int dir = db >> 2, b = db & 3;
  int p = blockIdx.x * 256 + threadIdx.x;
  const int* g = grids + ((size_t)dir * Bb + b) * HWp;
  int se = g[p];
  float* ob = out + (((size_t)dir * Bb + b) * Cc) * HWp + p;
  if (se < 0) {
#pragma unroll
    for (int c = 0; c < Cc; c++) ob[(size_t)c * HWp] = 0.f;
  } else {
    const float4* sp =
        (const float4*)(out_pts + (((size_t)dir * Bb + b) * Nn + se) * Cc);
#pragma unroll
    for (int c4 = 0; c4 < 8; c4++) {
      float4 v = sp[c4];
      ob[(size_t)(c4 * 4 + 0) * HWp] = v.x;
      ob[(size_t)(c4 * 4 + 1) * HWp] = v.y;
      ob[(size_t)(c4 * 4 + 2) * HWp] = v.z;
      ob[(size_t)(c4 * 4 + 3) * HWp] = v.w;
    }
  }
}

extern "C" void kernel_launch(void* const* d_in, const int* in_sizes, int n_in,
                              void* d_out, int out_size, void* d_ws, size_t ws_size,
                              hipStream_t stream) {
  const float* li_feats = (const float*)d_in[0];
  const int* li_coors = (const int*)d_in[1];
  const float* ra_feats = (const float*)d_in[2];
  const int* ra_coors = (const int*)d_in[3];
  const float* pos = (const float*)d_in[4];
  const float* in_w1 = (const float*)d_in[5];
  const float* in_b1 = (const float*)d_in[6];
  const float* out_w1 = (const float*)d_in[7];
  const float* out_b1 = (const float*)d_in[8];
  const float* in_w2 = (const float*)d_in[9];
  const float* in_b2 = (const float*)d_in[10];
  const float* out_w2 = (const float*)d_in[11];
  const float* out_b2 = (const float*)d_in[12];

  char* ws = (char*)d_ws;
  size_t off = 0;
  int* grids = (int*)(ws + off);
  off += (size_t)2 * Bb * HWp * 4;  // 3,276,800 B
  float* Qh = (float*)(ws + off);
  off += (size_t)2 * Bb * Nn * Cc * 4;  // 20,480,000 B
  float* Kp = (float*)(ws + off);
  off += (size_t)2 * Bb * Nn * Cc * 4;
  float* Vp = (float*)(ws + off);
  off += (size_t)2 * Bb * Nn * Cc * 4;
  float* out_pts = (float*)(ws + off);
  off += (size_t)2 * Bb * Nn * Cc * 4;
  float* posv = (float*)(ws + off);
  off += (size_t)2 * 9 * Cc * 4;  // total ~85.2 MB

  prep_k<<<803, 256, 0, stream>>>(grids, pos, in_w1, in_w2, posv);
  build_grid_k<<<(2 * Bb * Nn + 255) / 256, 256, 0, stream>>>(li_coors, ra_coors,
                                                              grids);
  dim3 gkv(Nn / 32, 2 * Bb);
  project_qkv_k<<<gkv, 256, 0, stream>>>(li_feats, ra_feats, in_w1, in_b1, in_w2,
                                         in_b2, Qh, Kp, Vp);
  dim3 ga((Nn + 255) / 256, 2 * Bb);
  attn_k<<<ga, 256, 0, stream>>>(li_coors, ra_coors, grids, Qh, Kp, Vp, posv, in_b1,
                                 in_b2, out_w1, out_b1, out_w2, out_b2, out_pts);
  dim3 gs(HWp / 256, 2 * Bb);
  scatter_k<<<gs, 256, 0, stream>>>(grids, out_pts, (float*)d_out);
}

// Round 5
// 97.707 us; speedup vs baseline: 3.7556x; 1.0653x over previous
//
#include <hip/hip_runtime.h>

constexpr int Hh = 320, Ww = 320, Cc = 32, Bb = 4, Nn = 20000;
constexpr int HWp = Hh * Ww;

// Fused prep: blocks [0,800) fill grids with -1 (int4 stores, full BW);
// blocks [800,803) compute posv[dir][l][c] = pos[l] @ wv_dir.T
__global__ __launch_bounds__(256) void prep_k(
    int* __restrict__ grids, const float* __restrict__ pos,
    const float* __restrict__ in_w1, const float* __restrict__ in_w2,
    float* __restrict__ posv) {
  int bx = blockIdx.x;
  if (bx < 800) {
    int i = bx * 256 + threadIdx.x;  // int4 index; 800*256 = 204800 = 2*4*HWp/4
    ((int4*)grids)[i] = make_int4(-1, -1, -1, -1);
    return;
  }
  int t = (bx - 800) * 256 + threadIdx.x;
  if (t >= 2 * 9 * Cc) return;
  int dir = t / (9 * Cc);
  int rem = t - dir * 9 * Cc;
  int l = rem / Cc, ch = rem - l * Cc;
  const float* w = (dir == 0 ? in_w1 : in_w2) + (2 * Cc + ch) * Cc;
  const float* pl = pos + l * Cc;
  float acc = 0.f;
  for (int j = 0; j < Cc; j++) acc += pl[j] * w[j];
  posv[t] = acc;
}

// Fused: blocks [0, 2504) = Q/K/V projection (register-tiled, 2 points/thread);
// blocks [2504, 3129) = build_grid scatter.
// Projection: block = 256 threads = 32 point-pairs x 8 channel-quads; 64 points.
// Each thread computes float4 of channels [4*c4..4*c4+3] of Q,K,V for TWO
// points, so each LDS weight read feeds 2x the FMAs (LDS-pipe was the bound).
constexpr int PROJ_BLOCKS_PER_SB = 313;  // ceil(20000/64)
constexpr int PROJ_TOTAL = PROJ_BLOCKS_PER_SB * 8;

__global__ __launch_bounds__(256) void project_build_k(
    const float* __restrict__ li_feats, const float* __restrict__ ra_feats,
    const int* __restrict__ li_coors, const int* __restrict__ ra_coors,
    const float* __restrict__ in_w1, const float* __restrict__ in_b1,
    const float* __restrict__ in_w2, const float* __restrict__ in_b2,
    float* __restrict__ Qh, float* __restrict__ Kp, float* __restrict__ Vp,
    int* __restrict__ grids) {
  int bx = blockIdx.x;
  if (bx >= PROJ_TOTAL) {
    int idx = (bx - PROJ_TOTAL) * 256 + threadIdx.x;
    if (idx >= 2 * Bb * Nn) return;
    int src = idx / (Bb * Nn);
    int r = idx - src * (Bb * Nn);
    int b = r / Nn, n = r - b * Nn;
    const int* c = (src == 0 ? li_coors : ra_coors) + ((size_t)b * Nn + n) * 2;
    grids[((size_t)src * Bb + b) * HWp + c[0] * Ww + c[1]] = n;
    return;
  }
  int sb = bx / PROJ_BLOCKS_PER_SB;
  int blk = bx - sb * PROJ_BLOCKS_PER_SB;
  int src = sb >> 2, b = sb & 3;
  // weights transposed, rows padded to 36 floats (9 float4) for bank spread
  __shared__ __align__(16) float wqT[32 * 36];
  __shared__ __align__(16) float wkT[32 * 36];
  __shared__ __align__(16) float wvT[32 * 36];
  __shared__ float bq[Cc];
  const float* wA = src == 0 ? in_w1 : in_w2;  // q weights: own direction
  const float* bA = src == 0 ? in_b1 : in_b2;
  const float* wB = src == 0 ? in_w2 : in_w1;  // k/v weights: other direction
  int t = threadIdx.x;
  for (int i = t; i < Cc * Cc; i += 256) {
    int c = i >> 5, j = i & 31;
    wqT[j * 36 + c] = wA[i];
    wkT[j * 36 + c] = wB[Cc * Cc + i];
    wvT[j * 36 + c] = wB[2 * Cc * Cc + i];
  }
  if (t < Cc) bq[t] = bA[t];
  __syncthreads();
  int pair = t >> 3, c4 = t & 7;
  int n = blk * 64 + pair * 2;  // n even; Nn even -> n+1 valid whenever n < Nn
  if (n >= Nn) return;
  const float* f0 = (src == 0 ? li_feats : ra_feats) + ((size_t)b * Nn + n) * Cc;
  float fv0[32], fv1[32];
  const float4* fp0 = (const float4*)f0;
  const float4* fp1 = (const float4*)(f0 + Cc);
#pragma unroll
  for (int j4 = 0; j4 < 8; j4++) {
    float4 u = fp0[j4];
    fv0[4 * j4 + 0] = u.x; fv0[4 * j4 + 1] = u.y;
    fv0[4 * j4 + 2] = u.z; fv0[4 * j4 + 3] = u.w;
    float4 v = fp1[j4];
    fv1[4 * j4 + 0] = v.x; fv1[4 * j4 + 1] = v.y;
    fv1[4 * j4 + 2] = v.z; fv1[4 * j4 + 3] = v.w;
  }
  const float4* wq4 = (const float4*)wqT;
  const float4* wk4 = (const float4*)wkT;
  const float4* wv4 = (const float4*)wvT;
  float4 bq4 = *(const float4*)(bq + c4 * 4);
  float4 aq0 = bq4, aq1 = bq4;
  float4 ak0 = make_float4(0.f, 0.f, 0.f, 0.f), ak1 = ak0;
  float4 av0 = ak0, av1 = ak0;
#pragma unroll
  for (int j = 0; j < 32; j++) {
    float fj0 = fv0[j], fj1 = fv1[j];
    float4 q4 = wq4[j * 9 + c4];
    float4 k4 = wk4[j * 9 + c4];
    float4 v4 = wv4[j * 9 + c4];
    aq0.x += fj0 * q4.x; aq0.y += fj0 * q4.y; aq0.z += fj0 * q4.z; aq0.w += fj0 * q4.w;
    aq1.x += fj1 * q4.x; aq1.y += fj1 * q4.y; aq1.z += fj1 * q4.z; aq1.w += fj1 * q4.w;
    ak0.x += fj0 * k4.x; ak0.y += fj0 * k4.y; ak0.z += fj0 * k4.z; ak0.w += fj0 * k4.w;
    ak1.x += fj1 * k4.x; ak1.y += fj1 * k4.y; ak1.z += fj1 * k4.z; ak1.w += fj1 * k4.w;
    av0.x += fj0 * v4.x; av0.y += fj0 * v4.y; av0.z += fj0 * v4.z; av0.w += fj0 * v4.w;
    av1.x += fj1 * v4.x; av1.y += fj1 * v4.y; av1.z += fj1 * v4.z; av1.w += fj1 * v4.w;
  }
  int dirq = src, dirkv = 1 - src;
  size_t qbase = (((size_t)dirq * Bb + b) * Nn + n) * Cc + c4 * 4;
  size_t kvbase = (((size_t)dirkv * Bb + b) * Nn + n) * Cc + c4 * 4;
  *(float4*)(Qh + qbase) = aq0;
  *(float4*)(Qh + qbase + Cc) = aq1;
  *(float4*)(Kp + kvbase) = ak0;
  *(float4*)(Kp + kvbase + Cc) = ak1;
  *(float4*)(Vp + kvbase) = av0;
  *(float4*)(Vp + kvbase + Cc) = av1;
}

// Per query point: 9-slot attention (2 heads of 16) + output projection.
__global__ __launch_bounds__(256) void attn_k(
    const int* __restrict__ li_coors, const int* __restrict__ ra_coors,
    const int* __restrict__ grids, const float* __restrict__ Qh,
    const float* __restrict__ Kp, const float* __restrict__ Vp,
    const float* __restrict__ posv, const float* __restrict__ in_b1,
    const float* __restrict__ in_b2, const float* __restrict__ out_w1,
    const float* __restrict__ out_b1, const float* __restrict__ out_w2,
    const float* __restrict__ out_b2, float* __restrict__ out_pts) {
  int db = blockIdx.y;
  int dir = db >> 2, b = db & 3;
  __shared__ __align__(16) float ow[Cc * Cc];
  __shared__ __align__(16) float pv[9 * Cc];
  __shared__ float obias[Cc], bk[Cc], bv[Cc];
  const float* owp = dir == 0 ? out_w1 : out_w2;
  const float* obp = dir == 0 ? out_b1 : out_b2;
  const float* ibp = dir == 0 ? in_b1 : in_b2;
  int t = threadIdx.x;
  for (int i = t; i < Cc * Cc; i += 256) ow[i] = owp[i];
  for (int i = t; i < 9 * Cc; i += 256) pv[i] = posv[dir * 9 * Cc + i];
  if (t < Cc) { obias[t] = obp[t]; bk[t] = ibp[Cc + t]; bv[t] = ibp[2 * Cc + t]; }
  __syncthreads();
  int n = blockIdx.x * 256 + t;
  if (n >= Nn) return;
  const int* qc = (dir == 0 ? li_coors : ra_coors) + ((size_t)b * Nn + n) * 2;
  int y = qc[0], x = qc[1];
  // kv grid: dir0 attends over ra (src1), dir1 over li (src0)
  const int* g = grids + ((size_t)(1 - dir) * Bb + b) * HWp;
  float4 qh4[8];
  const float4* qp = (const float4*)(Qh + (((size_t)dir * Bb + b) * Nn + n) * Cc);
#pragma unroll
  for (int j = 0; j < 8; j++) qh4[j] = qp[j];
  // invalid-slot score: qh . bk / 4 per head (reference keeps zero-K slots in softmax)
  float sinv0 = 0.f, sinv1 = 0.f;
  const float4* bk4 = (const float4*)bk;
#pragma unroll
  for (int j4 = 0; j4 < 4; j4++) {
    float4 b4 = bk4[j4], q4 = qh4[j4];
    sinv0 += q4.x * b4.x + q4.y * b4.y + q4.z * b4.z + q4.w * b4.w;
  }
#pragma unroll
  for (int j4 = 4; j4 < 8; j4++) {
    float4 b4 = bk4[j4], q4 = qh4[j4];
    sinv1 += q4.x * b4.x + q4.y * b4.y + q4.z * b4.z + q4.w * b4.w;
  }
  sinv0 *= 0.25f;
  sinv1 *= 0.25f;
  const int DY[9] = {0, -1, 1, 0, -1, 1, 0, -1, 1};
  const int DX[9] = {0, 0, 0, 1, 1, 1, -1, -1, -1};
  int sel[9];
  float s0[9], s1[9];
  const float* Kpb = Kp + ((size_t)dir * Bb + b) * Nn * Cc;
#pragma unroll
  for (int l = 0; l < 9; l++) {
    int cy = y + DY[l], cx = x + DX[l];
    int se = -1;
    if ((unsigned)cy < (unsigned)Hh && (unsigned)cx < (unsigned)Ww) se = g[cy * Ww + cx];
    sel[l] = se;
    float d0 = 0.f, d1 = 0.f;
    if (se >= 0) {
      const float4* kp = (const float4*)(Kpb + (size_t)se * Cc);
#pragma unroll
      for (int j4 = 0; j4 < 4; j4++) {
        float4 k4 = kp[j4], q4 = qh4[j4];
        d0 += q4.x * k4.x + q4.y * k4.y + q4.z * k4.z + q4.w * k4.w;
      }
#pragma unroll
      for (int j4 = 4; j4 < 8; j4++) {
        float4 k4 = kp[j4], q4 = qh4[j4];
        d1 += q4.x * k4.x + q4.y * k4.y + q4.z * k4.z + q4.w * k4.w;
      }
    }
    s0[l] = sinv0 + 0.25f * d0;
    s1[l] = sinv1 + 0.25f * d1;
  }
  float m0 = s0[0], m1 = s1[0];
#pragma unroll
  for (int l = 1; l < 9; l++) { m0 = fmaxf(m0, s0[l]); m1 = fmaxf(m1, s1[l]); }
  float sum0 = 0.f, sum1 = 0.f;
#pragma unroll
  for (int l = 0; l < 9; l++) {
    s0[l] = __expf(s0[l] - m0);
    s1[l] = __expf(s1[l] - m1);
    sum0 += s0[l];
    sum1 += s1[l];
  }
  float o[Cc];
#pragma unroll
  for (int j = 0; j < Cc; j++) o[j] = 0.f;
  const float* Vpb = Vp + ((size_t)dir * Bb + b) * Nn * Cc;
  const float4* pv4 = (const float4*)pv;
#pragma unroll
  for (int l = 0; l < 9; l++) {
    int se = sel[l];
    if (se >= 0) {
      const float4* vp = (const float4*)(Vpb + (size_t)se * Cc);
      float w0 = s0[l], w1 = s1[l];
#pragma unroll
      for (int j4 = 0; j4 < 8; j4++) {
        float4 v4 = vp[j4];
        float4 p4 = pv4[l * 8 + j4];
        float w = (j4 < 4) ? w0 : w1;
        o[j4 * 4 + 0] += w * (v4.x + p4.x);
        o[j4 * 4 + 1] += w * (v4.y + p4.y);
        o[j4 * 4 + 2] += w * (v4.z + p4.z);
        o[j4 * 4 + 3] += w * (v4.w + p4.w);
      }
    }
  }
  float r0 = 1.f / sum0, r1 = 1.f / sum1;
#pragma unroll
  for (int j = 0; j < 16; j++) o[j] = o[j] * r0 + bv[j];
#pragma unroll
  for (int j = 16; j < Cc; j++) o[j] = o[j] * r1 + bv[j];
  float* op = out_pts + (((size_t)dir * Bb + b) * Nn + n) * Cc;
  const float4* ow4 = (const float4*)ow;
#pragma unroll
  for (int c0 = 0; c0 < Cc; c0 += 4) {
    float a[4];
#pragma unroll
    for (int u = 0; u < 4; u++) {
      float acc = obias[c0 + u];
#pragma unroll
      for (int j4 = 0; j4 < 8; j4++) {
        float4 w4 = ow4[(c0 + u) * 8 + j4];
        acc += o[j4 * 4 + 0] * w4.x + o[j4 * 4 + 1] * w4.y + o[j4 * 4 + 2] * w4.z +
               o[j4 * 4 + 3] * w4.w;
      }
      a[u] = acc;
    }
    *(float4*)(op + c0) = make_float4(a[0], a[1], a[2], a[3]);
  }
}

// Inverted scatter: one thread per canvas pixel; channel stores are wave-coalesced.
__global__ __launch_bounds__(256) void scatter_k(
    const int* __restrict__ grids, const float* __restrict__ out_pts,
    float* __restrict__ out) {
  int db = blockIdx.y;
  int dir = db >> 2, b = db & 3;
  int p = blockIdx.x * 256 + threadIdx.x;
  const int* g = grids + ((size_t)dir * Bb + b) * HWp;
  int se = g[p];
  float* ob = out + (((size_t)dir * Bb + b) * Cc) * HWp + p;
  if (se < 0) {
#pragma unroll
    for (int c = 0; c < Cc; c++) ob[(size_t)c * HWp] = 0.f;
  } else {
    const float4* sp =
        (const float4*)(out_pts + (((size_t)dir * Bb + b) * Nn + se) * Cc);
#pragma unroll
    for (int c4 = 0; c4 < 8; c4++) {
      float4 v = sp[c4];
      ob[(size_t)(c4 * 4 + 0) * HWp] = v.x;
      ob[(size_t)(c4 * 4 + 1) * HWp] = v.y;
      ob[(size_t)(c4 * 4 + 2) * HWp] = v.z;
      ob[(size_t)(c4 * 4 + 3) * HWp] = v.w;
    }
  }
}

extern "C" void kernel_launch(void* const* d_in, const int* in_sizes, int n_in,
                              void* d_out, int out_size, void* d_ws, size_t ws_size,
                              hipStream_t stream) {
  const float* li_feats = (const float*)d_in[0];
  const int* li_coors = (const int*)d_in[1];
  const float* ra_feats = (const float*)d_in[2];
  const int* ra_coors = (const int*)d_in[3];
  const float* pos = (const float*)d_in[4];
  const float* in_w1 = (const float*)d_in[5];
  const float* in_b1 = (const float*)d_in[6];
  const float* out_w1 = (const float*)d_in[7];
  const float* out_b1 = (const float*)d_in[8];
  const float* in_w2 = (const float*)d_in[9];
  const float* in_b2 = (const float*)d_in[10];
  const float* out_w2 = (const float*)d_in[11];
  const float* out_b2 = (const float*)d_in[12];

  char* ws = (char*)d_ws;
  size_t off = 0;
  int* grids = (int*)(ws + off);
  off += (size_t)2 * Bb * HWp * 4;  // 3,276,800 B
  float* Qh = (float*)(ws + off);
  off += (size_t)2 * Bb * Nn * Cc * 4;  // 20,480,000 B
  float* Kp = (float*)(ws + off);
  off += (size_t)2 * Bb * Nn * Cc * 4;
  float* Vp = (float*)(ws + off);
  off += (size_t)2 * Bb * Nn * Cc * 4;
  float* out_pts = (float*)(ws + off);
  off += (size_t)2 * Bb * Nn * Cc * 4;
  float* posv = (float*)(ws + off);
  off += (size_t)2 * 9 * Cc * 4;  // total ~85.2 MB

  prep_k<<<803, 256, 0, stream>>>(grids, pos, in_w1, in_w2, posv);
  int build_blocks = (2 * Bb * Nn + 255) / 256;  // 625
  project_build_k<<<PROJ_TOTAL + build_blocks, 256, 0, stream>>>(
      li_feats, ra_feats, li_coors, ra_coors, in_w1, in_b1, in_w2, in_b2, Qh, Kp,
      Vp, grids);
  dim3 ga((Nn + 255) / 256, 2 * Bb);
  attn_k<<<ga, 256, 0, stream>>>(li_coors, ra_coors, grids, Qh, Kp, Vp, posv, in_b1,
                                 in_b2, out_w1, out_b1, out_w2, out_b2, out_pts);
  dim3 gs(HWp / 256, 2 * Bb);
  scatter_k<<<gs, 256, 0, stream>>>(grids, out_pts, (float*)d_out);
}